// Round 4
// baseline (84.409 us; speedup 1.0000x reference)
//
#include <hip/hip_runtime.h>
#include <math.h>

#define NROWS 65536
#define NC 1000
#define NC4 (NC / 4)   // 250 float4 per row
#define NBINS 15

// clang-native 4-float vector: accepted by __builtin_nontemporal_store
typedef float vfloat4 __attribute__((ext_vector_type(4)));

__global__ __launch_bounds__(256) void hbpe_kernel(
    const float* __restrict__ logits,
    const float* __restrict__ hist,
    float* __restrict__ out)
{
    // One wave per TWO rows: 2x memory-level parallelism + two independent
    // reduce chains to hide shuffle latency.
    const int w    = (int)((blockIdx.x * blockDim.x + threadIdx.x) >> 6);
    const int lane = (int)(threadIdx.x & 63);
    const int rowA = 2 * w;
    const int rowB = 2 * w + 1;

    const vfloat4* __restrict__ rpA = reinterpret_cast<const vfloat4*>(logits + (size_t)rowA * NC);
    const vfloat4* __restrict__ rpB = reinterpret_cast<const vfloat4*>(logits + (size_t)rowB * NC);
    vfloat4* __restrict__ opA       = reinterpret_cast<vfloat4*>(out + (size_t)rowA * NC);
    vfloat4* __restrict__ opB       = reinterpret_cast<vfloat4*>(out + (size_t)rowB * NC);

    // Issue all 8 dwordx4 loads before any use (32 KB in flight per wave)
    float va[16], vb[16];
    #pragma unroll
    for (int k = 0; k < 4; ++k) {
        const int i4 = k * 64 + lane;
        vfloat4 tA, tB;
        if (i4 < NC4) { tA = rpA[i4]; tB = rpB[i4]; }
        else {
            tA = (vfloat4){-INFINITY, -INFINITY, -INFINITY, -INFINITY};
            tB = (vfloat4){-INFINITY, -INFINITY, -INFINITY, -INFINITY};
        }
        va[4*k+0] = tA.x; va[4*k+1] = tA.y; va[4*k+2] = tA.z; va[4*k+3] = tA.w;
        vb[4*k+0] = tB.x; vb[4*k+1] = tB.y; vb[4*k+2] = tB.z; vb[4*k+3] = tB.w;
    }

    // Lane-local max + argmax for both rows (global column index, first-occurrence)
    float mA = -INFINITY, mB = -INFINITY;
    int   aA = 0x7fffffff, aB = 0x7fffffff;
    #pragma unroll
    for (int k = 0; k < 4; ++k) {
        const int i4 = k * 64 + lane;
        #pragma unroll
        for (int j = 0; j < 4; ++j) {
            const int c = i4 * 4 + j;
            const float xA = va[4*k + j];
            const float xB = vb[4*k + j];
            if (xA > mA || (xA == mA && c < aA)) { mA = xA; aA = c; }
            if (xB > mB || (xB == mB && c < aB)) { mB = xB; aB = c; }
        }
    }

    // Interleaved 64-lane butterfly (max, argmax) — two independent chains
    #pragma unroll
    for (int off = 32; off >= 1; off >>= 1) {
        const float omA = __shfl_xor(mA, off);
        const int   oaA = __shfl_xor(aA, off);
        const float omB = __shfl_xor(mB, off);
        const int   oaB = __shfl_xor(aB, off);
        if (omA > mA || (omA == mA && oaA < aA)) { mA = omA; aA = oaA; }
        if (omB > mB || (omB == mB && oaB < aB)) { mB = omB; aB = oaB; }
    }

    // exp(l - m) once, keep in registers; lane-local partial sums
    float sA = 0.0f, sB = 0.0f;
    #pragma unroll
    for (int k = 0; k < 16; ++k) {
        const float eA = __expf(va[k] - mA);   // -inf pad -> 0
        const float eB = __expf(vb[k] - mB);
        va[k] = eA; vb[k] = eB;
        sA += eA; sB += eB;
    }
    // Interleaved butterfly sums -> Z per row
    #pragma unroll
    for (int off = 32; off >= 1; off >>= 1) {
        sA += __shfl_xor(sA, off);
        sB += __shfl_xor(sB, off);
    }

    // conf = max softmax = 1/Z ; histc-style bin; sentinel fallback
    const float confA = 1.0f / sA;
    const float confB = 1.0f / sB;
    int binA = (int)(confA * (float)NBINS);
    int binB = (int)(confB * (float)NBINS);
    binA = binA < 0 ? 0 : (binA > NBINS - 1 ? NBINS - 1 : binA);
    binB = binB < 0 ? 0 : (binB > NBINS - 1 ? NBINS - 1 : binB);
    float postA = hist[binA];
    float postB = hist[binB];
    if (postA == -1.0f) postA = confA;
    if (postB == -1.0f) postB = confB;

    const float scaleA = (1.0f - postA) / (sA - 1.0f);
    const float scaleB = (1.0f - postB) / (sB - 1.0f);

    // Non-temporal stores: stream output past caches so logits stay L3-resident
    #pragma unroll
    for (int k = 0; k < 4; ++k) {
        const int i4 = k * 64 + lane;
        if (i4 < NC4) {
            vfloat4 oA, oB;
            oA.x = (i4*4 + 0 == aA) ? postA : scaleA * va[4*k+0];
            oA.y = (i4*4 + 1 == aA) ? postA : scaleA * va[4*k+1];
            oA.z = (i4*4 + 2 == aA) ? postA : scaleA * va[4*k+2];
            oA.w = (i4*4 + 3 == aA) ? postA : scaleA * va[4*k+3];
            oB.x = (i4*4 + 0 == aB) ? postB : scaleB * vb[4*k+0];
            oB.y = (i4*4 + 1 == aB) ? postB : scaleB * vb[4*k+1];
            oB.z = (i4*4 + 2 == aB) ? postB : scaleB * vb[4*k+2];
            oB.w = (i4*4 + 3 == aB) ? postB : scaleB * vb[4*k+3];
            __builtin_nontemporal_store(oA, &opA[i4]);
            __builtin_nontemporal_store(oB, &opB[i4]);
        }
    }
}

extern "C" void kernel_launch(void* const* d_in, const int* in_sizes, int n_in,
                              void* d_out, int out_size, void* d_ws, size_t ws_size,
                              hipStream_t stream) {
    const float* logits = (const float*)d_in[0];
    const float* hist   = (const float*)d_in[1];
    float* out          = (float*)d_out;

    // 1 wave per 2 rows, 4 waves per block -> 65536/8 = 8192 blocks
    const dim3 block(256);
    const dim3 grid(NROWS / 8);
    hbpe_kernel<<<grid, block, 0, stream>>>(logits, hist, out);
}

// Round 6
// 80.968 us; speedup vs baseline: 1.0425x; 1.0425x over previous
//
#include <hip/hip_runtime.h>
#include <math.h>

#define NROWS 65536
#define NC 1000
#define NC4 (NC / 4)   // 250 float4 per row
#define NBINS 15

// clang-native 4-float vector: accepted by __builtin_nontemporal_store
typedef float vfloat4 __attribute__((ext_vector_type(4)));

__global__ __launch_bounds__(256) void hbpe_kernel(
    const float* __restrict__ logits,
    const float* __restrict__ hist,
    float* __restrict__ out)
{
    const int row  = (int)((blockIdx.x * blockDim.x + threadIdx.x) >> 6);
    const int lane = (int)(threadIdx.x & 63);
    if (row >= NROWS) return;

    const vfloat4* __restrict__ rp = reinterpret_cast<const vfloat4*>(logits + (size_t)row * NC);
    vfloat4* __restrict__ op       = reinterpret_cast<vfloat4*>(out + (size_t)row * NC);

    // Load 16 elements per lane (coalesced float4, columns lane+64k interleaved).
    // Normal (caching) loads: logits ~250 MiB partially resident in Infinity Cache.
    float vv[16];
    #pragma unroll
    for (int k = 0; k < 4; ++k) {
        const int i4 = k * 64 + lane;
        vfloat4 t;
        if (i4 < NC4) t = rp[i4];
        else          t = (vfloat4){-INFINITY, -INFINITY, -INFINITY, -INFINITY};
        vv[4*k+0] = t.x; vv[4*k+1] = t.y; vv[4*k+2] = t.z; vv[4*k+3] = t.w;
    }

    // Lane-local max + argmax (global column index; first-occurrence tie-break)
    float m = -INFINITY;
    int   am = 0x7fffffff;
    #pragma unroll
    for (int k = 0; k < 4; ++k) {
        const int i4 = k * 64 + lane;
        #pragma unroll
        for (int j = 0; j < 4; ++j) {
            const float x = vv[4*k + j];
            const int   c = i4 * 4 + j;
            if (x > m || (x == m && c < am)) { m = x; am = c; }
        }
    }

    // 64-lane butterfly reduce: (max, argmax) — ties to lower column index
    #pragma unroll
    for (int off = 32; off >= 1; off >>= 1) {
        const float om = __shfl_xor(m, off);
        const int   oa = __shfl_xor(am, off);
        if (om > m || (om == m && oa < am)) { m = om; am = oa; }
    }

    // exp(l - m) once, keep in registers; lane-local partial sum
    float s = 0.0f;
    #pragma unroll
    for (int k = 0; k < 16; ++k) {
        const float e = __expf(vv[k] - m);   // -inf pad -> 0
        vv[k] = e;
        s += e;
    }
    // 64-lane butterfly sum -> Z (includes exp(0)=1 for the max element)
    #pragma unroll
    for (int off = 32; off >= 1; off >>= 1) {
        s += __shfl_xor(s, off);
    }

    // conf = max softmax = 1/Z ; histc-style bin; sentinel fallback
    const float conf = 1.0f / s;
    int bin = (int)(conf * (float)NBINS);
    bin = bin < 0 ? 0 : (bin > NBINS - 1 ? NBINS - 1 : bin);
    float post = hist[bin];
    if (post == -1.0f) post = conf;

    // out[j!=pred] = (1-post) * exp(l_j - m) / (Z - 1) ; out[pred] = post
    const float scale = (1.0f - post) / (s - 1.0f);

    // Non-temporal stores: stream output past the caches so logits stay
    // L3-resident across graph replays (output has zero reuse in the window).
    #pragma unroll
    for (int k = 0; k < 4; ++k) {
        const int i4 = k * 64 + lane;
        if (i4 < NC4) {
            vfloat4 o;
            o.x = (i4*4 + 0 == am) ? post : scale * vv[4*k+0];
            o.y = (i4*4 + 1 == am) ? post : scale * vv[4*k+1];
            o.z = (i4*4 + 2 == am) ? post : scale * vv[4*k+2];
            o.w = (i4*4 + 3 == am) ? post : scale * vv[4*k+3];
            __builtin_nontemporal_store(o, &op[i4]);
        }
    }
}

extern "C" void kernel_launch(void* const* d_in, const int* in_sizes, int n_in,
                              void* d_out, int out_size, void* d_ws, size_t ws_size,
                              hipStream_t stream) {
    const float* logits = (const float*)d_in[0];
    const float* hist   = (const float*)d_in[1];
    float* out          = (float*)d_out;

    // 1 wave per row, 4 waves per block -> 65536/4 = 16384 blocks
    const dim3 block(256);
    const dim3 grid(NROWS / 4);
    hbpe_kernel<<<grid, block, 0, stream>>>(logits, hist, out);
}